// Round 1
// baseline (741.527 us; speedup 1.0000x reference)
//
#include <hip/hip_runtime.h>

#define N_NODES 50000
#define N_EDGES 600000
#define D_IN 32
#define D_H 128

static inline int cdiv(int a, int b) { return (a + b - 1) / b; }

// ---------------- CSR build ----------------

__global__ void zero_kernel(int* __restrict__ p, int n) {
    int i = blockIdx.x * blockDim.x + threadIdx.x;
    if (i < n) p[i] = 0;
}

__global__ void count_kernel(const int* __restrict__ dst, int* __restrict__ cnt, int e) {
    int i = blockIdx.x * blockDim.x + threadIdx.x;
    if (i < e) atomicAdd(&cnt[dst[i]], 1);
}

// single block, 1024 threads: chunked serial + LDS Hillis-Steele scan
__global__ __launch_bounds__(1024) void scan_kernel(const int* __restrict__ cnt,
                                                    int* __restrict__ row_ptr,
                                                    int* __restrict__ fillp, int n) {
    __shared__ int lds[1024];
    int tid = threadIdx.x;
    const int C = (n + 1023) / 1024;  // 49
    int beg = tid * C;
    int end = beg + C; if (end > n) end = n;
    int s = 0;
    for (int i = beg; i < end && i >= 0; i++) s += cnt[i];
    lds[tid] = s;
    __syncthreads();
    for (int off = 1; off < 1024; off <<= 1) {
        int t = (tid >= off) ? lds[tid - off] : 0;
        __syncthreads();
        lds[tid] += t;
        __syncthreads();
    }
    int excl = lds[tid] - s;
    int run = excl;
    for (int i = beg; i < end && i >= 0; i++) {
        row_ptr[i] = run;
        fillp[i] = run;
        run += cnt[i];
    }
    if (tid == 1023) row_ptr[n] = lds[1023];
}

__global__ void fill_kernel(const int* __restrict__ src, const int* __restrict__ dst,
                            const float* __restrict__ w, int* __restrict__ fillp,
                            int* __restrict__ srcs, float* __restrict__ ws, int e) {
    int i = blockIdx.x * blockDim.x + threadIdx.x;
    if (i < e) {
        int d = dst[i];
        int pos = atomicAdd(&fillp[d], 1);
        srcs[pos] = src[i];
        ws[pos] = w[i];
    }
}

// ---------------- aggregation (pull, CSR) ----------------

// one wave per node, 128-dim features: lane handles float2
__global__ __launch_bounds__(256) void agg128_kernel(
    const float* __restrict__ x, const int* __restrict__ row_ptr,
    const int* __restrict__ srcs, const float* __restrict__ ws,
    float* __restrict__ agg, int n) {
    int wid = threadIdx.x >> 6, lane = threadIdx.x & 63;
    int node = blockIdx.x * 4 + wid;
    if (node >= n) return;
    int beg = row_ptr[node], end = row_ptr[node + 1];
    float2 acc = make_float2(0.f, 0.f);
    const float2* xv = (const float2*)x;
    for (int j = beg; j < end; j++) {
        int s = srcs[j];
        float w = ws[j];
        float2 v = xv[(size_t)s * 64 + lane];
        acc.x += v.x * w;
        acc.y += v.y * w;
    }
    ((float2*)agg)[(size_t)node * 64 + lane] = acc;
}

// 32-dim features: lanes 0..31 each handle one float
__global__ __launch_bounds__(256) void agg32_kernel(
    const float* __restrict__ x, const int* __restrict__ row_ptr,
    const int* __restrict__ srcs, const float* __restrict__ ws,
    float* __restrict__ agg, int n) {
    int wid = threadIdx.x >> 6, lane = threadIdx.x & 63;
    int node = blockIdx.x * 4 + wid;
    if (node >= n || lane >= 32) return;
    int beg = row_ptr[node], end = row_ptr[node + 1];
    float acc = 0.f;
    for (int j = beg; j < end; j++) {
        int s = srcs[j];
        float w = ws[j];
        acc += x[(size_t)s * 32 + lane] * w;
    }
    agg[(size_t)node * 32 + lane] = acc;
}

// ---------------- fused linear: out = relu(agg@Wrel^T + b + x@Wroot^T) [+skip relu] ----------------

template <int K, bool SKIP>
__global__ __launch_bounds__(128) void lin_kernel(
    const float* __restrict__ agg, const float* __restrict__ x,
    const float* __restrict__ Wrel, const float* __restrict__ b,
    const float* __restrict__ Wroot, float* __restrict__ out, int n) {
    constexpr int TN = 16;
    __shared__ float tile[TN][2 * K];
    int o = threadIdx.x;  // output feature 0..127
    int n0 = blockIdx.x * TN;

    // stage [agg | x] rows for TN nodes into LDS (float4, coalesced)
    constexpr int ROWV = 2 * K / 4;       // float4s per row
    constexpr int VECS = TN * ROWV;
    for (int i = o; i < VECS; i += 128) {
        int row = i / ROWV;
        int col4 = i % ROWV;
        int node = n0 + row;
        float4 v;
        if (node < n) {
            if (col4 < K / 4)
                v = ((const float4*)(agg + (size_t)node * K))[col4];
            else
                v = ((const float4*)(x + (size_t)node * K))[col4 - K / 4];
        } else {
            v = make_float4(0.f, 0.f, 0.f, 0.f);
        }
        ((float4*)&tile[row][0])[col4] = v;
    }
    __syncthreads();

    float acc[TN];
    float bias = b[o];
#pragma unroll
    for (int t = 0; t < TN; t++) acc[t] = bias;

    const float4* wr = (const float4*)(Wrel + (size_t)o * K);
    const float4* wo = (const float4*)(Wroot + (size_t)o * K);
#pragma unroll 4
    for (int k4 = 0; k4 < K / 4; k4++) {
        float4 w = wr[k4];
#pragma unroll
        for (int t = 0; t < TN; t++) {
            float4 v = ((const float4*)&tile[t][0])[k4];
            acc[t] += w.x * v.x + w.y * v.y + w.z * v.z + w.w * v.w;
        }
    }
#pragma unroll 4
    for (int k4 = 0; k4 < K / 4; k4++) {
        float4 w = wo[k4];
#pragma unroll
        for (int t = 0; t < TN; t++) {
            float4 v = ((const float4*)&tile[t][0])[K / 4 + k4];
            acc[t] += w.x * v.x + w.y * v.y + w.z * v.z + w.w * v.w;
        }
    }

#pragma unroll
    for (int t = 0; t < TN; t++) {
        int node = n0 + t;
        if (node >= n) break;
        float h = fmaxf(acc[t], 0.f);
        if (SKIP) h = fmaxf(h + x[(size_t)node * K + o], 0.f);
        out[(size_t)node * D_H + o] = h;
    }
}

// ---------------- launch ----------------

extern "C" void kernel_launch(void* const* d_in, const int* in_sizes, int n_in,
                              void* d_out, int out_size, void* d_ws, size_t ws_size,
                              hipStream_t stream) {
    const float* z     = (const float*)d_in[0];
    const int*   eidx  = (const int*)d_in[1];
    const float* ew    = (const float*)d_in[2];
    // d_in[3] = batch (unused)
    const float* Wrel0  = (const float*)d_in[4];
    const float* brel0  = (const float*)d_in[5];
    const float* Wroot0 = (const float*)d_in[6];
    const float* Wrel   = (const float*)d_in[7];
    const float* brel   = (const float*)d_in[8];
    const float* Wroot  = (const float*)d_in[9];

    const int* src = eidx;            // edge_index[0]
    const int* dst = eidx + N_EDGES;  // edge_index[1]

    char* p = (char*)d_ws;
    auto alloc = [&](size_t bytes) {
        void* r = (void*)p;
        p += (bytes + 255) & ~(size_t)255;
        return r;
    };
    int*   cnt   = (int*)alloc((size_t)N_NODES * 4);
    int*   rowp  = (int*)alloc((size_t)(N_NODES + 1) * 4);
    int*   fillp = (int*)alloc((size_t)N_NODES * 4);
    int*   srcs  = (int*)alloc((size_t)N_EDGES * 4);
    float* wss   = (float*)alloc((size_t)N_EDGES * 4);
    float* agg   = (float*)alloc((size_t)N_NODES * D_H * 4);
    float* h0    = (float*)alloc((size_t)N_NODES * D_H * 4);
    float* h1    = (float*)alloc((size_t)N_NODES * D_H * 4);
    float* outp  = (float*)d_out;

    // CSR build (by destination)
    zero_kernel<<<cdiv(N_NODES, 256), 256, 0, stream>>>(cnt, N_NODES);
    count_kernel<<<cdiv(N_EDGES, 256), 256, 0, stream>>>(dst, cnt, N_EDGES);
    scan_kernel<<<1, 1024, 0, stream>>>(cnt, rowp, fillp, N_NODES);
    fill_kernel<<<cdiv(N_EDGES, 256), 256, 0, stream>>>(src, dst, ew, fillp, srcs, wss, N_EDGES);

    const int aggGrid = cdiv(N_NODES, 4);
    const int linGrid = cdiv(N_NODES, 16);

    // L0: 32 -> 128, no skip
    agg32_kernel<<<aggGrid, 256, 0, stream>>>(z, rowp, srcs, wss, agg, N_NODES);
    lin_kernel<32, false><<<linGrid, 128, 0, stream>>>(agg, z, Wrel0, brel0, Wroot0, h0, N_NODES);
    // L1: skip
    agg128_kernel<<<aggGrid, 256, 0, stream>>>(h0, rowp, srcs, wss, agg, N_NODES);
    lin_kernel<128, true><<<linGrid, 128, 0, stream>>>(agg, h0, Wrel, brel, Wroot, h1, N_NODES);
    // L2: skip
    agg128_kernel<<<aggGrid, 256, 0, stream>>>(h1, rowp, srcs, wss, agg, N_NODES);
    lin_kernel<128, true><<<linGrid, 128, 0, stream>>>(agg, h1, Wrel + 128 * 128, brel + 128,
                                                       Wroot + 128 * 128, h0, N_NODES);
    // L3: no skip -> d_out
    agg128_kernel<<<aggGrid, 256, 0, stream>>>(h0, rowp, srcs, wss, agg, N_NODES);
    lin_kernel<128, false><<<linGrid, 128, 0, stream>>>(agg, h0, Wrel + 2 * 128 * 128, brel + 2 * 128,
                                                        Wroot + 2 * 128 * 128, outp, N_NODES);
}

// Round 2
// 321.991 us; speedup vs baseline: 2.3029x; 2.3029x over previous
//
#include <hip/hip_runtime.h>

#define N_NODES 50000
#define N_EDGES 600000
#define D_IN 32
#define D_H 128

typedef __attribute__((ext_vector_type(8))) short short8;
typedef __attribute__((ext_vector_type(4))) float f32x4;

static inline int cdiv(int a, int b) { return (a + b - 1) / b; }

// bf16 round-to-nearest-even (finite inputs)
__device__ inline unsigned short f2bf(float f) {
    unsigned int b = __float_as_uint(f);
    return (unsigned short)((b + 0x7FFFu + ((b >> 16) & 1u)) >> 16);
}
__device__ inline unsigned int pack_bf16(float a, float b) {
    return (unsigned int)f2bf(a) | ((unsigned int)f2bf(b) << 16);
}

// ---------------- CSR build ----------------

__global__ void zero_kernel(int* __restrict__ p, int n) {
    int i = blockIdx.x * blockDim.x + threadIdx.x;
    if (i < n) p[i] = 0;
}

__global__ void count_kernel(const int* __restrict__ dst, int* __restrict__ cnt, int e) {
    int i = blockIdx.x * blockDim.x + threadIdx.x;
    if (i < e) atomicAdd(&cnt[dst[i]], 1);
}

// hierarchical scan: per-block scan + block sums
__global__ __launch_bounds__(256) void scanA_kernel(const int* __restrict__ cnt,
                                                    int* __restrict__ rowp,
                                                    int* __restrict__ bsum, int n) {
    __shared__ int s[256];
    int tid = threadIdx.x;
    int i = blockIdx.x * 256 + tid;
    int v = (i < n) ? cnt[i] : 0;
    s[tid] = v;
    __syncthreads();
#pragma unroll
    for (int off = 1; off < 256; off <<= 1) {
        int t = (tid >= off) ? s[tid - off] : 0;
        __syncthreads();
        s[tid] += t;
        __syncthreads();
    }
    if (i < n) rowp[i] = s[tid] - v;  // intra-block exclusive
    if (tid == 255) bsum[blockIdx.x] = s[255];
}

__global__ __launch_bounds__(256) void scanB_kernel(const int* __restrict__ bsum,
                                                    int* __restrict__ boff,
                                                    int* __restrict__ rowp, int nb, int n) {
    __shared__ int s[256];
    int tid = threadIdx.x;
    int v = (tid < nb) ? bsum[tid] : 0;
    s[tid] = v;
    __syncthreads();
#pragma unroll
    for (int off = 1; off < 256; off <<= 1) {
        int t = (tid >= off) ? s[tid - off] : 0;
        __syncthreads();
        s[tid] += t;
        __syncthreads();
    }
    if (tid < nb) boff[tid] = s[tid] - v;
    if (tid == nb - 1) rowp[n] = s[tid];
}

__global__ __launch_bounds__(256) void scanC_kernel(int* __restrict__ rowp,
                                                    int* __restrict__ fillp,
                                                    const int* __restrict__ boff, int n) {
    int i = blockIdx.x * 256 + threadIdx.x;
    if (i < n) {
        int v = rowp[i] + boff[blockIdx.x];
        rowp[i] = v;
        fillp[i] = v;
    }
}

__global__ void fill_kernel(const int* __restrict__ src, const int* __restrict__ dst,
                            const float* __restrict__ w, int* __restrict__ fillp,
                            int2* __restrict__ ep, int e) {
    int i = blockIdx.x * blockDim.x + threadIdx.x;
    if (i < e) {
        int pos = atomicAdd(&fillp[dst[i]], 1);
        ep[pos] = make_int2(src[i], __float_as_int(w[i]));
    }
}

// ---------------- aggregation (pull, CSR, packed edges) ----------------

__global__ __launch_bounds__(256) void agg128_kernel(
    const float* __restrict__ x, const int* __restrict__ rowp,
    const int2* __restrict__ ep, float* __restrict__ agg, int n) {
    int wid = threadIdx.x >> 6, lane = threadIdx.x & 63;
    int node = blockIdx.x * 4 + wid;
    if (node >= n) return;
    int j = rowp[node], end = rowp[node + 1];
    float2 acc = make_float2(0.f, 0.f);
    const float2* xv = (const float2*)x;
    for (; j + 2 <= end; j += 2) {
        int2 e0 = ep[j], e1 = ep[j + 1];
        float2 v0 = xv[(size_t)e0.x * 64 + lane];
        float2 v1 = xv[(size_t)e1.x * 64 + lane];
        float w0 = __int_as_float(e0.y), w1 = __int_as_float(e1.y);
        acc.x += v0.x * w0; acc.y += v0.y * w0;
        acc.x += v1.x * w1; acc.y += v1.y * w1;
    }
    if (j < end) {
        int2 e0 = ep[j];
        float2 v0 = xv[(size_t)e0.x * 64 + lane];
        float w0 = __int_as_float(e0.y);
        acc.x += v0.x * w0; acc.y += v0.y * w0;
    }
    ((float2*)agg)[(size_t)node * 64 + lane] = acc;
}

// 32-dim: 2 nodes per wave (full lane utilization)
__global__ __launch_bounds__(256) void agg32_kernel(
    const float* __restrict__ x, const int* __restrict__ rowp,
    const int2* __restrict__ ep, float* __restrict__ agg, int n) {
    int wid = threadIdx.x >> 6, lane = threadIdx.x & 63;
    int node = blockIdx.x * 8 + wid * 2 + (lane >> 5);
    int f = lane & 31;
    if (node >= n) return;
    int j = rowp[node], end = rowp[node + 1];
    float acc = 0.f;
    for (; j + 2 <= end; j += 2) {
        int2 e0 = ep[j], e1 = ep[j + 1];
        acc += x[(size_t)e0.x * 32 + f] * __int_as_float(e0.y);
        acc += x[(size_t)e1.x * 32 + f] * __int_as_float(e1.y);
    }
    if (j < end) {
        int2 e0 = ep[j];
        acc += x[(size_t)e0.x * 32 + f] * __int_as_float(e0.y);
    }
    agg[(size_t)node * 32 + f] = acc;
}

// ---------------- weight pre-conversion to bf16 (combined [o][K2] = [Wrel|Wroot]) ----------------

__global__ void wconv_kernel(const float* __restrict__ Wrel0, const float* __restrict__ Wroot0,
                             const float* __restrict__ Wrel, const float* __restrict__ Wroot,
                             unsigned short* __restrict__ W0, unsigned short* __restrict__ W1) {
    int i = blockIdx.x * 256 + threadIdx.x;
    if (i < 128 * 64) {
        int o = i >> 6, k = i & 63;
        float v = (k < 32) ? Wrel0[o * 32 + k] : Wroot0[o * 32 + (k - 32)];
        W0[i] = f2bf(v);
    }
    if (i < 3 * 128 * 256) {
        int L = i >> 15;
        int r = i & 32767;
        int o = r >> 8, k = r & 255;
        float v = (k < 128) ? Wrel[L * 16384 + o * 128 + k]
                            : Wroot[L * 16384 + o * 128 + (k - 128)];
        W1[i] = f2bf(v);
    }
}

// ---------------- fused linear via MFMA ----------------
// out[n][128] = relu( [agg|x][n][2K] @ W2[128][2K]^T + b ) (+skip relu)
// A staged in LDS pre-packed in fragment order: 16B unit index = (mt*NKS+ks)*64 + lane.
// mfma_f32_16x16x32_bf16: A row=l&15, k=(l>>4)*8+j; B col=l&15, same k; D col=l&15, row=(l>>4)*4+j.

template <int KH, bool SKIP>
__global__ __launch_bounds__(256) void lin_kernel(
    const float* __restrict__ agg, const float* __restrict__ x,
    const unsigned short* __restrict__ W2, const float* __restrict__ bias,
    float* __restrict__ out, int n) {
    constexpr int K2 = 2 * KH;
    constexpr int NKS = K2 / 32;
    constexpr int LOGNKS = (NKS == 2) ? 1 : 3;
    constexpr int SLOTS = 16 * K2;  // 8B slots = 64 rows * K2 * 2B / 8
    __shared__ uint2 Abuf[SLOTS];
    const int tid = threadIdx.x;
    const int n0 = blockIdx.x * 64;

    // stage [agg|x] rows 64 x K2 as bf16, packed so GEMM-phase reads are lane-linear
#pragma unroll
    for (int it = 0; it < SLOTS / 256; it++) {
        int d = tid + it * 256;
        int jh = d & 1;
        int l = (d >> 1) & 63;
        int ks = (d >> 7) & (NKS - 1);
        int mt = d >> (7 + LOGNKS);
        int r = mt * 16 + (l & 15);
        int k = ks * 32 + ((l >> 4) << 3) + jh * 4;
        int node = n0 + r;
        float4 v = make_float4(0.f, 0.f, 0.f, 0.f);
        if (node < n) {
            v = (k < KH) ? *(const float4*)(agg + (size_t)node * KH + k)
                         : *(const float4*)(x + (size_t)node * KH + (k - KH));
        }
        Abuf[d] = make_uint2(pack_bf16(v.x, v.y), pack_bf16(v.z, v.w));
    }
    __syncthreads();

    const int w = tid >> 6, l = tid & 63;
    const int lo16 = l & 15, hi = l >> 4;

    f32x4 acc[4][2];
#pragma unroll
    for (int nt = 0; nt < 2; nt++) {
        float bv = bias[w * 32 + nt * 16 + lo16];
#pragma unroll
        for (int mt = 0; mt < 4; mt++) acc[mt][nt] = (f32x4){bv, bv, bv, bv};
    }

    const short8* Afr = (const short8*)Abuf;
#pragma unroll
    for (int ks = 0; ks < NKS; ks++) {
        short8 bfr[2];
#pragma unroll
        for (int nt = 0; nt < 2; nt++) {
            int o = w * 32 + nt * 16 + lo16;
            bfr[nt] = *(const short8*)(W2 + (size_t)o * K2 + ks * 32 + hi * 8);
        }
#pragma unroll
        for (int mt = 0; mt < 4; mt++) {
            short8 afr = Afr[(mt * NKS + ks) * 64 + l];
            acc[mt][0] = __builtin_amdgcn_mfma_f32_16x16x32_bf16(afr, bfr[0], acc[mt][0], 0, 0, 0);
            acc[mt][1] = __builtin_amdgcn_mfma_f32_16x16x32_bf16(afr, bfr[1], acc[mt][1], 0, 0, 0);
        }
    }

#pragma unroll
    for (int mt = 0; mt < 4; mt++) {
#pragma unroll
        for (int j = 0; j < 4; j++) {
            int node = n0 + mt * 16 + hi * 4 + j;
            if (node < n) {
#pragma unroll
                for (int nt = 0; nt < 2; nt++) {
                    int o = w * 32 + nt * 16 + lo16;
                    float v = acc[mt][nt][j];
                    v = fmaxf(v, 0.f);
                    if (SKIP) v = fmaxf(v + x[(size_t)node * D_H + o], 0.f);
                    out[(size_t)node * D_H + o] = v;
                }
            }
        }
    }
}

// ---------------- launch ----------------

extern "C" void kernel_launch(void* const* d_in, const int* in_sizes, int n_in,
                              void* d_out, int out_size, void* d_ws, size_t ws_size,
                              hipStream_t stream) {
    const float* z      = (const float*)d_in[0];
    const int*   eidx   = (const int*)d_in[1];
    const float* ew     = (const float*)d_in[2];
    const float* Wrel0  = (const float*)d_in[4];
    const float* brel0  = (const float*)d_in[5];
    const float* Wroot0 = (const float*)d_in[6];
    const float* Wrel   = (const float*)d_in[7];
    const float* brel   = (const float*)d_in[8];
    const float* Wroot  = (const float*)d_in[9];

    const int* src = eidx;
    const int* dst = eidx + N_EDGES;

    char* p = (char*)d_ws;
    auto alloc = [&](size_t bytes) {
        void* r = (void*)p;
        p += (bytes + 255) & ~(size_t)255;
        return r;
    };
    const int NB = cdiv(N_NODES, 256);  // 196
    int*   cnt   = (int*)alloc((size_t)N_NODES * 4);
    int*   rowp  = (int*)alloc((size_t)(N_NODES + 1) * 4);
    int*   fillp = (int*)alloc((size_t)N_NODES * 4);
    int*   bsum  = (int*)alloc((size_t)NB * 4);
    int*   boff  = (int*)alloc((size_t)NB * 4);
    int2*  epack = (int2*)alloc((size_t)N_EDGES * 8);
    float* aggb  = (float*)alloc((size_t)N_NODES * D_H * 4);
    float* h0    = (float*)alloc((size_t)N_NODES * D_H * 4);
    float* h1    = (float*)alloc((size_t)N_NODES * D_H * 4);
    unsigned short* W0bf = (unsigned short*)alloc((size_t)128 * 64 * 2);
    unsigned short* W1bf = (unsigned short*)alloc((size_t)3 * 128 * 256 * 2);
    float* outp = (float*)d_out;

    // weights -> bf16 (once per call)
    wconv_kernel<<<cdiv(3 * 128 * 256, 256), 256, 0, stream>>>(Wrel0, Wroot0, Wrel, Wroot, W0bf, W1bf);

    // CSR build
    zero_kernel<<<cdiv(N_NODES, 256), 256, 0, stream>>>(cnt, N_NODES);
    count_kernel<<<cdiv(N_EDGES, 256), 256, 0, stream>>>(dst, cnt, N_EDGES);
    scanA_kernel<<<NB, 256, 0, stream>>>(cnt, rowp, bsum, N_NODES);
    scanB_kernel<<<1, 256, 0, stream>>>(bsum, boff, rowp, NB, N_NODES);
    scanC_kernel<<<NB, 256, 0, stream>>>(rowp, fillp, boff, N_NODES);
    fill_kernel<<<cdiv(N_EDGES, 256), 256, 0, stream>>>(src, dst, ew, fillp, epack, N_EDGES);

    const int agg128Grid = cdiv(N_NODES, 4);
    const int agg32Grid  = cdiv(N_NODES, 8);
    const int linGrid    = cdiv(N_NODES, 64);

    // L0: 32 -> 128
    agg32_kernel<<<agg32Grid, 256, 0, stream>>>(z, rowp, epack, aggb, N_NODES);
    lin_kernel<32, false><<<linGrid, 256, 0, stream>>>(aggb, z, W0bf, brel0, h0, N_NODES);
    // L1 (skip)
    agg128_kernel<<<agg128Grid, 256, 0, stream>>>(h0, rowp, epack, aggb, N_NODES);
    lin_kernel<128, true><<<linGrid, 256, 0, stream>>>(aggb, h0, W1bf, brel, h1, N_NODES);
    // L2 (skip)
    agg128_kernel<<<agg128Grid, 256, 0, stream>>>(h1, rowp, epack, aggb, N_NODES);
    lin_kernel<128, true><<<linGrid, 256, 0, stream>>>(aggb, h1, W1bf + 32768, brel + 128, h0, N_NODES);
    // L3 (no skip) -> out
    agg128_kernel<<<agg128Grid, 256, 0, stream>>>(h0, rowp, epack, aggb, N_NODES);
    lin_kernel<128, false><<<linGrid, 256, 0, stream>>>(aggb, h0, W1bf + 65536, brel + 256, outp, N_NODES);
}

// Round 3
// 256.852 us; speedup vs baseline: 2.8870x; 1.2536x over previous
//
#include <hip/hip_runtime.h>

#define N_NODES 50000
#define N_EDGES 600000
#define D_IN 32
#define D_H 128

typedef __attribute__((ext_vector_type(8))) short short8;
typedef __attribute__((ext_vector_type(4))) float f32x4;

static inline int cdiv(int a, int b) { return (a + b - 1) / b; }

// bf16 round-to-nearest-even (finite inputs)
__device__ inline unsigned short f2bf(float f) {
    unsigned int b = __float_as_uint(f);
    return (unsigned short)((b + 0x7FFFu + ((b >> 16) & 1u)) >> 16);
}
__device__ inline unsigned int pack_bf16(float a, float b) {
    return (unsigned int)f2bf(a) | ((unsigned int)f2bf(b) << 16);
}
__device__ inline float bf_lo(unsigned int u) { return __uint_as_float(u << 16); }
__device__ inline float bf_hi(unsigned int u) { return __uint_as_float(u & 0xFFFF0000u); }

// ---------------- prep: z -> bf16 ----------------

__global__ void zconv_kernel(const float* __restrict__ z, unsigned int* __restrict__ zbf) {
    int i = blockIdx.x * 256 + threadIdx.x;  // one uint2 (4 elems) per thread
    if (i < N_NODES * D_IN / 4) {
        float4 v = ((const float4*)z)[i];
        ((uint2*)zbf)[i] = make_uint2(pack_bf16(v.x, v.y), pack_bf16(v.z, v.w));
    }
}

// ---------------- prep: weights -> bf16 (combined [o][K2] = [Wrel|Wroot]) ----------------

__global__ void wconv_kernel(const float* __restrict__ Wrel0, const float* __restrict__ Wroot0,
                             const float* __restrict__ Wrel, const float* __restrict__ Wroot,
                             unsigned short* __restrict__ W0, unsigned short* __restrict__ W1) {
    int i = blockIdx.x * 256 + threadIdx.x;
    if (i < 128 * 64) {
        int o = i >> 6, k = i & 63;
        float v = (k < 32) ? Wrel0[o * 32 + k] : Wroot0[o * 32 + (k - 32)];
        W0[i] = f2bf(v);
    }
    if (i < 3 * 128 * 256) {
        int L = i >> 15;
        int r = i & 32767;
        int o = r >> 8, k = r & 255;
        float v = (k < 128) ? Wrel[L * 16384 + o * 128 + k]
                            : Wroot[L * 16384 + o * 128 + (k - 128)];
        W1[i] = f2bf(v);
    }
}

// ---------------- CSR build ----------------

__global__ void zero_kernel(int* __restrict__ p, int n) {
    int i = blockIdx.x * blockDim.x + threadIdx.x;
    if (i < n) p[i] = 0;
}

__global__ void count_kernel(const int* __restrict__ dst, int* __restrict__ cnt, int e) {
    int i = blockIdx.x * blockDim.x + threadIdx.x;
    if (i < e) atomicAdd(&cnt[dst[i]], 1);
}

__global__ __launch_bounds__(256) void scanA_kernel(const int* __restrict__ cnt,
                                                    int* __restrict__ rowp,
                                                    int* __restrict__ bsum, int n) {
    __shared__ int s[256];
    int tid = threadIdx.x;
    int i = blockIdx.x * 256 + tid;
    int v = (i < n) ? cnt[i] : 0;
    s[tid] = v;
    __syncthreads();
#pragma unroll
    for (int off = 1; off < 256; off <<= 1) {
        int t = (tid >= off) ? s[tid - off] : 0;
        __syncthreads();
        s[tid] += t;
        __syncthreads();
    }
    if (i < n) rowp[i] = s[tid] - v;
    if (tid == 255) bsum[blockIdx.x] = s[255];
}

__global__ __launch_bounds__(256) void scanB_kernel(const int* __restrict__ bsum,
                                                    int* __restrict__ boff,
                                                    int* __restrict__ rowp, int nb, int n) {
    __shared__ int s[256];
    int tid = threadIdx.x;
    int v = (tid < nb) ? bsum[tid] : 0;
    s[tid] = v;
    __syncthreads();
#pragma unroll
    for (int off = 1; off < 256; off <<= 1) {
        int t = (tid >= off) ? s[tid - off] : 0;
        __syncthreads();
        s[tid] += t;
        __syncthreads();
    }
    if (tid < nb) boff[tid] = s[tid] - v;
    if (tid == nb - 1) rowp[n] = s[tid];
}

__global__ __launch_bounds__(256) void scanC_kernel(int* __restrict__ rowp,
                                                    int* __restrict__ fillp,
                                                    const int* __restrict__ boff, int n) {
    int i = blockIdx.x * 256 + threadIdx.x;
    if (i < n) {
        int v = rowp[i] + boff[blockIdx.x];
        rowp[i] = v;
        fillp[i] = v;
    }
}

__global__ void fill_kernel(const int* __restrict__ src, const int* __restrict__ dst,
                            const float* __restrict__ w, int* __restrict__ fillp,
                            int2* __restrict__ ep, int e) {
    int i = blockIdx.x * blockDim.x + threadIdx.x;
    if (i < e) {
        int pos = atomicAdd(&fillp[dst[i]], 1);
        ep[pos] = make_int2(src[i], __float_as_int(w[i]));
    }
}

// ---------------- aggregation (pull, CSR, bf16 features) ----------------

// 128-dim bf16: one wave per node, lane owns one uint (2 features); unroll-4 for MLP
__global__ __launch_bounds__(256) void agg128_kernel(
    const unsigned int* __restrict__ xbf, const int* __restrict__ rowp,
    const int2* __restrict__ ep, unsigned int* __restrict__ aggbf, int n) {
    int wid = threadIdx.x >> 6, lane = threadIdx.x & 63;
    int node = blockIdx.x * 4 + wid;
    if (node >= n) return;
    int j = rowp[node], end = rowp[node + 1];
    float ax = 0.f, ay = 0.f;
    for (; j + 4 <= end; j += 4) {
        int2 e0 = ep[j], e1 = ep[j + 1], e2 = ep[j + 2], e3 = ep[j + 3];
        unsigned int v0 = xbf[(size_t)e0.x * 64 + lane];
        unsigned int v1 = xbf[(size_t)e1.x * 64 + lane];
        unsigned int v2 = xbf[(size_t)e2.x * 64 + lane];
        unsigned int v3 = xbf[(size_t)e3.x * 64 + lane];
        float w0 = __int_as_float(e0.y), w1 = __int_as_float(e1.y);
        float w2 = __int_as_float(e2.y), w3 = __int_as_float(e3.y);
        ax += bf_lo(v0) * w0; ay += bf_hi(v0) * w0;
        ax += bf_lo(v1) * w1; ay += bf_hi(v1) * w1;
        ax += bf_lo(v2) * w2; ay += bf_hi(v2) * w2;
        ax += bf_lo(v3) * w3; ay += bf_hi(v3) * w3;
    }
    for (; j < end; j++) {
        int2 e0 = ep[j];
        unsigned int v0 = xbf[(size_t)e0.x * 64 + lane];
        float w0 = __int_as_float(e0.y);
        ax += bf_lo(v0) * w0; ay += bf_hi(v0) * w0;
    }
    aggbf[(size_t)node * 64 + lane] = pack_bf16(ax, ay);
}

// 32-dim f32 input z: 2 nodes per wave, lane owns one feature; bf16 output via lane-pair pack
__global__ __launch_bounds__(256) void agg32_kernel(
    const float* __restrict__ z, const int* __restrict__ rowp,
    const int2* __restrict__ ep, unsigned int* __restrict__ aggbf, int n) {
    int wid = threadIdx.x >> 6, lane = threadIdx.x & 63;
    int node = blockIdx.x * 8 + wid * 2 + (lane >> 5);
    int f = lane & 31;
    if (node >= n) return;
    int j = rowp[node], end = rowp[node + 1];
    float acc = 0.f;
    for (; j + 4 <= end; j += 4) {
        int2 e0 = ep[j], e1 = ep[j + 1], e2 = ep[j + 2], e3 = ep[j + 3];
        float x0 = z[(size_t)e0.x * 32 + f];
        float x1 = z[(size_t)e1.x * 32 + f];
        float x2 = z[(size_t)e2.x * 32 + f];
        float x3 = z[(size_t)e3.x * 32 + f];
        acc += x0 * __int_as_float(e0.y) + x1 * __int_as_float(e1.y)
             + x2 * __int_as_float(e2.y) + x3 * __int_as_float(e3.y);
    }
    for (; j < end; j++) {
        int2 e0 = ep[j];
        acc += z[(size_t)e0.x * 32 + f] * __int_as_float(e0.y);
    }
    float hi = __shfl_down(acc, 1);
    if (!(f & 1)) aggbf[(size_t)node * 16 + (f >> 1)] = pack_bf16(acc, hi);
}

// ---------------- fused linear via MFMA (bf16 in, bf16/f32 out) ----------------
// out[n][128] = relu( [agg|x][n][2K] @ W2[128][2K]^T + b ) (+skip relu)
// A staged in LDS pre-packed in fragment order; 16B unit u = (mt*NKS+ks)*64 + lane.

template <int KH, bool SKIP, bool FINAL>
__global__ __launch_bounds__(256) void lin_kernel(
    const unsigned short* __restrict__ agg, const unsigned short* __restrict__ x,
    const unsigned short* __restrict__ W2, const float* __restrict__ bias,
    void* __restrict__ outv, int n) {
    constexpr int K2 = 2 * KH;
    constexpr int NKS = K2 / 32;
    constexpr int LOGNKS = (NKS == 2) ? 1 : 3;
    constexpr int SLOTS = 16 * K2;  // 8B slots = 64 rows * K2 * 2B / 8
    __shared__ uint2 Abuf[SLOTS];
    const int tid = threadIdx.x;
    const int n0 = blockIdx.x * 64;

#pragma unroll
    for (int it = 0; it < SLOTS / 256; it++) {
        int d = tid + it * 256;
        int jh = d & 1;
        int l = (d >> 1) & 63;
        int ks = (d >> 7) & (NKS - 1);
        int mt = d >> (7 + LOGNKS);
        int r = mt * 16 + (l & 15);
        int k = ks * 32 + ((l >> 4) << 3) + jh * 4;
        int node = n0 + r;
        uint2 v = make_uint2(0u, 0u);
        if (node < n) {
            v = (k < KH) ? *(const uint2*)(agg + (size_t)node * KH + k)
                         : *(const uint2*)(x + (size_t)node * KH + (k - KH));
        }
        Abuf[d] = v;
    }
    __syncthreads();

    const int w = tid >> 6, l = tid & 63;
    const int lo16 = l & 15, hi = l >> 4;

    f32x4 acc[4][2];
#pragma unroll
    for (int nt = 0; nt < 2; nt++) {
        float bv = bias[w * 32 + nt * 16 + lo16];
#pragma unroll
        for (int mt = 0; mt < 4; mt++) acc[mt][nt] = (f32x4){bv, bv, bv, bv};
    }

    const short8* Afr = (const short8*)Abuf;
#pragma unroll
    for (int ks = 0; ks < NKS; ks++) {
        short8 bfr[2];
#pragma unroll
        for (int nt = 0; nt < 2; nt++) {
            int o = w * 32 + nt * 16 + lo16;
            bfr[nt] = *(const short8*)(W2 + (size_t)o * K2 + ks * 32 + hi * 8);
        }
#pragma unroll
        for (int mt = 0; mt < 4; mt++) {
            short8 afr = Afr[(mt * NKS + ks) * 64 + l];
            acc[mt][0] = __builtin_amdgcn_mfma_f32_16x16x32_bf16(afr, bfr[0], acc[mt][0], 0, 0, 0);
            acc[mt][1] = __builtin_amdgcn_mfma_f32_16x16x32_bf16(afr, bfr[1], acc[mt][1], 0, 0, 0);
        }
    }

#pragma unroll
    for (int mt = 0; mt < 4; mt++) {
#pragma unroll
        for (int j = 0; j < 4; j++) {
            int node = n0 + mt * 16 + hi * 4 + j;
            if (node < n) {
#pragma unroll
                for (int nt = 0; nt < 2; nt++) {
                    int o = w * 32 + nt * 16 + lo16;
                    float v = acc[mt][nt][j];
                    v = fmaxf(v, 0.f);
                    if (SKIP) {
                        float xs = __uint_as_float((unsigned int)x[(size_t)node * D_H + o] << 16);
                        v = fmaxf(v + xs, 0.f);
                    }
                    if (FINAL)
                        ((float*)outv)[(size_t)node * D_H + o] = v;
                    else
                        ((unsigned short*)outv)[(size_t)node * D_H + o] = f2bf(v);
                }
            }
        }
    }
}

// ---------------- launch ----------------

extern "C" void kernel_launch(void* const* d_in, const int* in_sizes, int n_in,
                              void* d_out, int out_size, void* d_ws, size_t ws_size,
                              hipStream_t stream) {
    const float* z      = (const float*)d_in[0];
    const int*   eidx   = (const int*)d_in[1];
    const float* ew     = (const float*)d_in[2];
    const float* Wrel0  = (const float*)d_in[4];
    const float* brel0  = (const float*)d_in[5];
    const float* Wroot0 = (const float*)d_in[6];
    const float* Wrel   = (const float*)d_in[7];
    const float* brel   = (const float*)d_in[8];
    const float* Wroot  = (const float*)d_in[9];

    const int* src = eidx;
    const int* dst = eidx + N_EDGES;

    char* p = (char*)d_ws;
    auto alloc = [&](size_t bytes) {
        void* r = (void*)p;
        p += (bytes + 255) & ~(size_t)255;
        return r;
    };
    const int NB = cdiv(N_NODES, 256);  // 196
    int*   cnt   = (int*)alloc((size_t)N_NODES * 4);
    int*   rowp  = (int*)alloc((size_t)(N_NODES + 1) * 4);
    int*   fillp = (int*)alloc((size_t)N_NODES * 4);
    int*   bsum  = (int*)alloc((size_t)NB * 4);
    int*   boff  = (int*)alloc((size_t)NB * 4);
    int2*  epack = (int2*)alloc((size_t)N_EDGES * 8);
    unsigned int* zbf   = (unsigned int*)alloc((size_t)N_NODES * D_IN * 2);
    unsigned int* aggbf = (unsigned int*)alloc((size_t)N_NODES * D_H * 2);
    unsigned int* h0    = (unsigned int*)alloc((size_t)N_NODES * D_H * 2);
    unsigned int* h1    = (unsigned int*)alloc((size_t)N_NODES * D_H * 2);
    unsigned short* W0bf = (unsigned short*)alloc((size_t)128 * 64 * 2);
    unsigned short* W1bf = (unsigned short*)alloc((size_t)3 * 128 * 256 * 2);
    float* outp = (float*)d_out;

    // prep
    zconv_kernel<<<cdiv(N_NODES * D_IN / 4, 256), 256, 0, stream>>>(z, zbf);
    wconv_kernel<<<cdiv(3 * 128 * 256, 256), 256, 0, stream>>>(Wrel0, Wroot0, Wrel, Wroot, W0bf, W1bf);

    // CSR build
    zero_kernel<<<cdiv(N_NODES, 256), 256, 0, stream>>>(cnt, N_NODES);
    count_kernel<<<cdiv(N_EDGES, 256), 256, 0, stream>>>(dst, cnt, N_EDGES);
    scanA_kernel<<<NB, 256, 0, stream>>>(cnt, rowp, bsum, N_NODES);
    scanB_kernel<<<1, 256, 0, stream>>>(bsum, boff, rowp, NB, N_NODES);
    scanC_kernel<<<NB, 256, 0, stream>>>(rowp, fillp, boff, N_NODES);
    fill_kernel<<<cdiv(N_EDGES, 256), 256, 0, stream>>>(src, dst, ew, fillp, epack, N_EDGES);

    const int agg128Grid = cdiv(N_NODES, 4);
    const int agg32Grid  = cdiv(N_NODES, 8);
    const int linGrid    = cdiv(N_NODES, 64);

    // L0: 32 -> 128 (no skip)
    agg32_kernel<<<agg32Grid, 256, 0, stream>>>(z, rowp, epack, aggbf, N_NODES);
    lin_kernel<32, false, false><<<linGrid, 256, 0, stream>>>(
        (const unsigned short*)aggbf, (const unsigned short*)zbf, W0bf, brel0, h0, N_NODES);
    // L1 (skip)
    agg128_kernel<<<agg128Grid, 256, 0, stream>>>(h0, rowp, epack, aggbf, N_NODES);
    lin_kernel<128, true, false><<<linGrid, 256, 0, stream>>>(
        (const unsigned short*)aggbf, (const unsigned short*)h0, W1bf, brel, h1, N_NODES);
    // L2 (skip)
    agg128_kernel<<<agg128Grid, 256, 0, stream>>>(h1, rowp, epack, aggbf, N_NODES);
    lin_kernel<128, true, false><<<linGrid, 256, 0, stream>>>(
        (const unsigned short*)aggbf, (const unsigned short*)h1, W1bf + 32768, brel + 128, h0, N_NODES);
    // L3 (no skip) -> d_out (f32)
    agg128_kernel<<<agg128Grid, 256, 0, stream>>>(h0, rowp, epack, aggbf, N_NODES);
    lin_kernel<128, false, true><<<linGrid, 256, 0, stream>>>(
        (const unsigned short*)aggbf, (const unsigned short*)h0, W1bf + 65536, brel + 256, outp, N_NODES);
}